// Round 4
// baseline (1810.984 us; speedup 1.0000x reference)
//
#include <hip/hip_runtime.h>

// HeteroGNN forward (SAGE mean-aggr, two relations), MI355X.
//
// Round 4: fix the transform regression. Round-3's per-thread W arrays were
// demoted to scratch (VGPR_Count=64 for 128 floats of state -> scratch
// thrash, 437us). Now W columns live in 32 NAMED float4 registers (statically
// indexed, cannot be demoted), __launch_bounds__(256,2) budgets 256 VGPRs.
// Row data is read via same-address broadcast float4 loads (no LDS, no
// barriers, one wave per row); in-place safe since a row is read and written
// only by its owning wave.

#define EPB 16384   // edges per chunk in partitioned CSR-build kernels

// ---------------------------------------------------------------------------
// Phase A: partitioned count (writes to cnt partition b%8 only)
// ---------------------------------------------------------------------------
__global__ void count_part_kernel(const int* __restrict__ src, const int* __restrict__ dst,
                                  int* __restrict__ cnt, int Nr, int nE,
                                  float invR, float invU)
{
    const int p  = blockIdx.x & 7;
    const int c  = blockIdx.x >> 3;
    const int e0 = c * EPB;
    const int e1 = min(e0 + EPB, nE);
    for (int e = e0 + threadIdx.x; e < e1; e += blockDim.x) {
        const int dr = dst[e];
        const int su = src[e];
        if (min(7, (int)(dr * invR)) == p) atomicAdd(&cnt[dr], 1);
        if (min(7, (int)(su * invU)) == p) atomicAdd(&cnt[Nr + su], 1);
    }
}

#define SCAN_BS 2048   // elements per block in scan (256 thr x 8)

__global__ void scan_block_kernel(const int* __restrict__ cnt, int* __restrict__ off,
                                  int* __restrict__ partial, int N)
{
    __shared__ int sdata[256];
    const int t = threadIdx.x;
    const long long base = (long long)blockIdx.x * SCAN_BS + (long long)t * 8;
    int v[8];
    int s = 0;
    #pragma unroll
    for (int k = 0; k < 8; ++k) {
        long long i = base + k;
        v[k] = (i < N) ? cnt[i] : 0;
        s += v[k];
    }
    sdata[t] = s;
    __syncthreads();
    for (int d = 1; d < 256; d <<= 1) {
        int val = (t >= d) ? sdata[t - d] : 0;
        __syncthreads();
        if (t >= d) sdata[t] += val;
        __syncthreads();
    }
    if (t == 255) partial[blockIdx.x] = sdata[255];
    int run = sdata[t] - s;   // exclusive prefix for this thread's chunk
    #pragma unroll
    for (int k = 0; k < 8; ++k) {
        long long i = base + k;
        if (i < N) off[i] = run;
        run += v[k];
    }
}

__global__ void scan_partials_kernel(int* __restrict__ partial, int nb)
{
    __shared__ int sdata[256];
    const int t = threadIdx.x;
    int v = (t < nb) ? partial[t] : 0;
    sdata[t] = v;
    __syncthreads();
    for (int d = 1; d < 256; d <<= 1) {
        int val = (t >= d) ? sdata[t - d] : 0;
        __syncthreads();
        if (t >= d) sdata[t] += val;
        __syncthreads();
    }
    if (t < nb) partial[t] = sdata[t] - v;   // exclusive
}

__global__ void scan_addback_kernel(int* __restrict__ off, const int* __restrict__ partial,
                                    int N, int total)
{
    long long i = (long long)blockIdx.x * blockDim.x + threadIdx.x;
    if (i < N) off[i] += partial[i / SCAN_BS];
    if (i == 0) off[N] = total;
}

// ---------------------------------------------------------------------------
// Phase A: partitioned bucket scatter (XCD-local writes)
// ---------------------------------------------------------------------------
__global__ void scatter_part_kernel(const int* __restrict__ src, const int* __restrict__ dst,
                                    const int* __restrict__ off, int* __restrict__ cnt,
                                    int* __restrict__ nbr, int Nr, int nE,
                                    float invR, float invU)
{
    const int p  = blockIdx.x & 7;
    const int c  = blockIdx.x >> 3;
    const int e0 = c * EPB;
    const int e1 = min(e0 + EPB, nE);
    for (int e = e0 + threadIdx.x; e < e1; e += blockDim.x) {
        const int dr = dst[e];
        const int su = src[e];
        if (min(7, (int)(dr * invR)) == p) {
            int pos = off[dr] + atomicSub(&cnt[dr], 1) - 1;
            nbr[pos] = su;
        }
        if (min(7, (int)(su * invU)) == p) {
            int pos = off[Nr + su] + atomicSub(&cnt[Nr + su], 1) - 1;
            nbr[pos] = dr;
        }
    }
}

// ---------------------------------------------------------------------------
// Phase B: atomic-free gather + mean.  16 lanes per node; lane owns 4 feats.
// ---------------------------------------------------------------------------
__device__ __forceinline__ void f4add(float4& a, const float4 v) {
    a.x += v.x; a.y += v.y; a.z += v.z; a.w += v.w;
}

__global__ void gather_mean_kernel(const float* __restrict__ x,
                                   const int* __restrict__ off,
                                   const int* __restrict__ nbr,
                                   float* __restrict__ agg, int N)
{
    const int tid  = blockIdx.x * blockDim.x + threadIdx.x;
    const int g    = tid >> 4;
    if (g >= N) return;
    const int lane = tid & 15;
    const int c    = lane << 2;

    const int beg = off[g];
    const int end = off[g + 1];

    float4 a0 = {0,0,0,0}, a1 = {0,0,0,0}, a2 = {0,0,0,0}, a3 = {0,0,0,0};
    int j = beg;
    for (; j + 4 <= end; j += 4) {
        const int s0 = nbr[j], s1 = nbr[j+1], s2 = nbr[j+2], s3 = nbr[j+3];
        f4add(a0, *reinterpret_cast<const float4*>(x + ((long long)s0 << 6) + c));
        f4add(a1, *reinterpret_cast<const float4*>(x + ((long long)s1 << 6) + c));
        f4add(a2, *reinterpret_cast<const float4*>(x + ((long long)s2 << 6) + c));
        f4add(a3, *reinterpret_cast<const float4*>(x + ((long long)s3 << 6) + c));
    }
    for (; j < end; ++j) {
        f4add(a0, *reinterpret_cast<const float4*>(x + ((long long)nbr[j] << 6) + c));
    }
    f4add(a0, a1); f4add(a2, a3); f4add(a0, a2);

    const float inv = 1.0f / (float)max(end - beg, 1);
    float4 r; r.x = a0.x * inv; r.y = a0.y * inv; r.z = a0.z * inv; r.w = a0.w * inv;
    *reinterpret_cast<float4*>(agg + ((long long)g << 6) + c) = r;
}

// ---------------------------------------------------------------------------
// Phase C: register-W transform, take 2. 32 NAMED float4 registers hold the
// lane's W columns (no arrays -> no scratch demotion). One wave per row; row
// values arrive via same-address broadcast float4 loads. No LDS, no barriers.
//   out = relu( agg @ Wl + bl + xroot @ Wr ), in-place over agg.
// ---------------------------------------------------------------------------
#define LW(nm, W, d0) \
    float4 nm; nm.x = W[(d0) * 64 + h]; nm.y = W[((d0) + 1) * 64 + h]; \
    nm.z = W[((d0) + 2) * 64 + h]; nm.w = W[((d0) + 3) * 64 + h];

#define ST(i) { \
    const float4 a = pa[i]; const float4 b = px[i]; \
    acc += a.x * wl##i.x + a.y * wl##i.y + a.z * wl##i.z + a.w * wl##i.w; \
    acc += b.x * wr##i.x + b.y * wr##i.y + b.z * wr##i.z + b.w * wr##i.w; }

__global__ __launch_bounds__(256, 2)
void transform_v2_kernel(const float* __restrict__ agg,
                         const float* __restrict__ xroot,
                         const float* __restrict__ Wl,
                         const float* __restrict__ bl,
                         const float* __restrict__ Wr,
                         float* __restrict__ out, int N)
{
    const int h = threadIdx.x & 63;
    const int wid    = (blockIdx.x * blockDim.x + threadIdx.x) >> 6;
    const int nwaves = (gridDim.x * blockDim.x) >> 6;

    LW(wl0,  Wl, 0)  LW(wl1,  Wl, 4)  LW(wl2,  Wl, 8)  LW(wl3,  Wl, 12)
    LW(wl4,  Wl, 16) LW(wl5,  Wl, 20) LW(wl6,  Wl, 24) LW(wl7,  Wl, 28)
    LW(wl8,  Wl, 32) LW(wl9,  Wl, 36) LW(wl10, Wl, 40) LW(wl11, Wl, 44)
    LW(wl12, Wl, 48) LW(wl13, Wl, 52) LW(wl14, Wl, 56) LW(wl15, Wl, 60)
    LW(wr0,  Wr, 0)  LW(wr1,  Wr, 4)  LW(wr2,  Wr, 8)  LW(wr3,  Wr, 12)
    LW(wr4,  Wr, 16) LW(wr5,  Wr, 20) LW(wr6,  Wr, 24) LW(wr7,  Wr, 28)
    LW(wr8,  Wr, 32) LW(wr9,  Wr, 36) LW(wr10, Wr, 40) LW(wr11, Wr, 44)
    LW(wr12, Wr, 48) LW(wr13, Wr, 52) LW(wr14, Wr, 56) LW(wr15, Wr, 60)
    const float bias = bl[h];

    for (int r = wid; r < N; r += nwaves) {
        const float4* pa = reinterpret_cast<const float4*>(agg)   + ((long long)r << 4);
        const float4* px = reinterpret_cast<const float4*>(xroot) + ((long long)r << 4);
        float acc = bias;
        ST(0)  ST(1)  ST(2)  ST(3)  ST(4)  ST(5)  ST(6)  ST(7)
        ST(8)  ST(9)  ST(10) ST(11) ST(12) ST(13) ST(14) ST(15)
        out[((long long)r << 6) + h] = fmaxf(acc, 0.0f);
    }
}

// ---------------------------------------------------------------------------
// Fallback (round-1) kernels, used only if ws_size is too small for CSR.
// ---------------------------------------------------------------------------
__global__ void edge_scatter_kernel(
    const float* __restrict__ xu, const float* __restrict__ xr,
    const int* __restrict__ src, const int* __restrict__ dst,
    float* __restrict__ agg_r, float* __restrict__ agg_u,
    float* __restrict__ deg_r, float* __restrict__ deg_u,
    int nE)
{
    int tid  = blockIdx.x * blockDim.x + threadIdx.x;
    int e    = tid >> 4;
    if (e >= nE) return;
    int lane = tid & 15;
    int su = src[e];
    int dr = dst[e];
    if (lane == 0) {
        atomicAdd(&deg_r[dr], 1.0f);
        atomicAdd(&deg_u[su], 1.0f);
    }
    const float4 a = *reinterpret_cast<const float4*>(xu + ((long long)su << 6) + (lane << 2));
    const float4 b = *reinterpret_cast<const float4*>(xr + ((long long)dr << 6) + (lane << 2));
    float* pr = agg_r + ((long long)dr << 6) + (lane << 2);
    float* pu = agg_u + ((long long)su << 6) + (lane << 2);
    atomicAdd(pr + 0, a.x); atomicAdd(pr + 1, a.y);
    atomicAdd(pr + 2, a.z); atomicAdd(pr + 3, a.w);
    atomicAdd(pu + 0, b.x); atomicAdd(pu + 1, b.y);
    atomicAdd(pu + 2, b.z); atomicAdd(pu + 3, b.w);
}

__global__ void transform_kernel(
    const float* __restrict__ agg, const float* __restrict__ deg,
    const float* __restrict__ xroot,
    const float* __restrict__ Wl, const float* __restrict__ bl,
    const float* __restrict__ Wr,
    float* __restrict__ out, int N)
{
    __shared__ float sWl[64 * 64];
    __shared__ float sWr[64 * 64];
    __shared__ float sb[64];
    __shared__ float sAgg[4][64];
    __shared__ float sX[4][64];

    const int t = threadIdx.x;
    for (int i = t; i < 64 * 64; i += 256) {
        sWl[i] = Wl[i];
        sWr[i] = Wr[i];
    }
    if (t < 64) sb[t] = bl[t];
    __syncthreads();

    const int rg = t >> 6;
    const int h  = t & 63;

    for (long long r0 = (long long)blockIdx.x * 4; r0 < N; r0 += (long long)gridDim.x * 4) {
        const long long r = r0 + rg;
        if (r < N) {
            float inv = 1.0f / fmaxf(deg[r], 1.0f);
            sAgg[rg][h] = agg[(r << 6) + h] * inv;
            sX[rg][h]   = xroot[(r << 6) + h];
        }
        __syncthreads();
        if (r < N) {
            float acc = sb[h];
            #pragma unroll
            for (int d = 0; d < 64; ++d) {
                acc += sAgg[rg][d] * sWl[d * 64 + h] + sX[rg][d] * sWr[d * 64 + h];
            }
            out[(r << 6) + h] = fmaxf(acc, 0.0f);
        }
        __syncthreads();
    }
}

extern "C" void kernel_launch(void* const* d_in, const int* in_sizes, int n_in,
                              void* d_out, int out_size, void* d_ws, size_t ws_size,
                              hipStream_t stream)
{
    const float* xu    = (const float*)d_in[0];
    const float* xr    = (const float*)d_in[1];
    const int*   src   = (const int*)  d_in[2];
    const int*   dst   = (const int*)  d_in[3];
    const float* Wl_ur = (const float*)d_in[4];
    const float* bl_ur = (const float*)d_in[5];
    const float* Wr_ur = (const float*)d_in[6];
    const float* Wl_ru = (const float*)d_in[7];
    const float* bl_ru = (const float*)d_in[8];
    const float* Wr_ru = (const float*)d_in[9];

    const int Nu = in_sizes[0] / 64;
    const int Nr = in_sizes[1] / 64;
    const int nE = in_sizes[2];
    const int NN = Nr + Nu;

    float* out   = (float*)d_out;
    float* agg_r = out;                        // [Nr,64]
    float* agg_u = out + (long long)Nr * 64;   // [Nu,64]

    // ---- workspace layout (ints) ----
    int* cnt     = (int*)d_ws;                  // [NN]
    int* off     = cnt + NN;                    // [NN+1]
    int* partial = off + NN + 1;                // [256]
    int* nbr     = partial + 256;               // [2E]
    const size_t need = ((size_t)NN + (size_t)NN + 1 + 256 + 2ull * nE) * sizeof(int);

    if (ws_size >= need) {
        // ---------------- CSR path ----------------
        hipMemsetAsync(cnt, 0, (size_t)NN * sizeof(int), stream);

        const float invR = 8.0f / (float)Nr;
        const float invU = 8.0f / (float)Nu;
        const int nChunks = (nE + EPB - 1) / EPB;
        const int grid    = nChunks * 8;

        count_part_kernel<<<grid, 256, 0, stream>>>(src, dst, cnt, Nr, nE, invR, invU);

        const int nScanBlocks = (NN + SCAN_BS - 1) / SCAN_BS;   // <= 256
        scan_block_kernel<<<nScanBlocks, 256, 0, stream>>>(cnt, off, partial, NN);
        scan_partials_kernel<<<1, 256, 0, stream>>>(partial, nScanBlocks);
        scan_addback_kernel<<<(NN + 255) / 256, 256, 0, stream>>>(off, partial, NN, 2 * nE);

        scatter_part_kernel<<<grid, 256, 0, stream>>>(src, dst, off, cnt, nbr, Nr, nE, invR, invU);

        // gathers (mean fused in; writes every output row)
        {
            const long long tr = (long long)Nr * 16;
            gather_mean_kernel<<<(int)((tr + 255) / 256), 256, 0, stream>>>(
                xu, off, nbr, agg_r, Nr);
            const long long tu = (long long)Nu * 16;
            gather_mean_kernel<<<(int)((tu + 255) / 256), 256, 0, stream>>>(
                xr, off + Nr, nbr, agg_u, Nu);
        }

        transform_v2_kernel<<<2048, 256, 0, stream>>>(
            agg_r, xr, Wl_ur, bl_ur, Wr_ur, agg_r, Nr);
        transform_v2_kernel<<<2048, 256, 0, stream>>>(
            agg_u, xu, Wl_ru, bl_ru, Wr_ru, agg_u, Nu);
    } else {
        // ---------------- fallback: atomic path ----------------
        float* deg_r = (float*)d_ws;
        float* deg_u = deg_r + Nr;
        hipMemsetAsync(d_out, 0, (size_t)out_size * sizeof(float), stream);
        hipMemsetAsync(d_ws, 0, (size_t)NN * sizeof(float), stream);

        const long long total = (long long)nE * 16;
        edge_scatter_kernel<<<(int)((total + 255) / 256), 256, 0, stream>>>(
            xu, xr, src, dst, agg_r, agg_u, deg_r, deg_u, nE);

        transform_kernel<<<2048, 256, 0, stream>>>(
            agg_r, deg_r, xr, Wl_ur, bl_ur, Wr_ur, agg_r, Nr);
        transform_kernel<<<2048, 256, 0, stream>>>(
            agg_u, deg_u, xu, Wl_ru, bl_ru, Wr_ru, agg_u, Nu);
    }
}

// Round 5
// 831.534 us; speedup vs baseline: 2.1779x; 2.1779x over previous
//
#include <hip/hip_runtime.h>

// HeteroGNN forward (SAGE mean-aggr, two relations), MI355X.
//
// Round 5 transform (v3): lane = row. Each lane streams its OWN row into 16
// statically-indexed float4 regs (coalesced-ish lane-distinct loads), holds
// all 64 outputs in registers, and multiplies by W read as WAVE-UNIFORM
// scalars (compiler -> s_load through the constant cache; v_fmac_f32 takes
// one SGPR operand). No LDS, no broadcast global loads (round-4's 10x
// traffic bug), no runtime-indexed arrays (round-3's scratch demotion).
// __launch_bounds__(64,2) budgets 256 VGPRs for ~150 live regs.

#define EPB 16384   // edges per chunk in partitioned CSR-build kernels

// ---------------------------------------------------------------------------
// Phase A: partitioned count (writes to cnt partition b%8 only)
// ---------------------------------------------------------------------------
__global__ void count_part_kernel(const int* __restrict__ src, const int* __restrict__ dst,
                                  int* __restrict__ cnt, int Nr, int nE,
                                  float invR, float invU)
{
    const int p  = blockIdx.x & 7;
    const int c  = blockIdx.x >> 3;
    const int e0 = c * EPB;
    const int e1 = min(e0 + EPB, nE);
    for (int e = e0 + threadIdx.x; e < e1; e += blockDim.x) {
        const int dr = dst[e];
        const int su = src[e];
        if (min(7, (int)(dr * invR)) == p) atomicAdd(&cnt[dr], 1);
        if (min(7, (int)(su * invU)) == p) atomicAdd(&cnt[Nr + su], 1);
    }
}

#define SCAN_BS 2048   // elements per block in scan (256 thr x 8)

__global__ void scan_block_kernel(const int* __restrict__ cnt, int* __restrict__ off,
                                  int* __restrict__ partial, int N)
{
    __shared__ int sdata[256];
    const int t = threadIdx.x;
    const long long base = (long long)blockIdx.x * SCAN_BS + (long long)t * 8;
    int v[8];
    int s = 0;
    #pragma unroll
    for (int k = 0; k < 8; ++k) {
        long long i = base + k;
        v[k] = (i < N) ? cnt[i] : 0;
        s += v[k];
    }
    sdata[t] = s;
    __syncthreads();
    for (int d = 1; d < 256; d <<= 1) {
        int val = (t >= d) ? sdata[t - d] : 0;
        __syncthreads();
        if (t >= d) sdata[t] += val;
        __syncthreads();
    }
    if (t == 255) partial[blockIdx.x] = sdata[255];
    int run = sdata[t] - s;   // exclusive prefix for this thread's chunk
    #pragma unroll
    for (int k = 0; k < 8; ++k) {
        long long i = base + k;
        if (i < N) off[i] = run;
        run += v[k];
    }
}

__global__ void scan_partials_kernel(int* __restrict__ partial, int nb)
{
    __shared__ int sdata[256];
    const int t = threadIdx.x;
    int v = (t < nb) ? partial[t] : 0;
    sdata[t] = v;
    __syncthreads();
    for (int d = 1; d < 256; d <<= 1) {
        int val = (t >= d) ? sdata[t - d] : 0;
        __syncthreads();
        if (t >= d) sdata[t] += val;
        __syncthreads();
    }
    if (t < nb) partial[t] = sdata[t] - v;   // exclusive
}

__global__ void scan_addback_kernel(int* __restrict__ off, const int* __restrict__ partial,
                                    int N, int total)
{
    long long i = (long long)blockIdx.x * blockDim.x + threadIdx.x;
    if (i < N) off[i] += partial[i / SCAN_BS];
    if (i == 0) off[N] = total;
}

// ---------------------------------------------------------------------------
// Phase A: partitioned bucket scatter (XCD-local writes)
// ---------------------------------------------------------------------------
__global__ void scatter_part_kernel(const int* __restrict__ src, const int* __restrict__ dst,
                                    const int* __restrict__ off, int* __restrict__ cnt,
                                    int* __restrict__ nbr, int Nr, int nE,
                                    float invR, float invU)
{
    const int p  = blockIdx.x & 7;
    const int c  = blockIdx.x >> 3;
    const int e0 = c * EPB;
    const int e1 = min(e0 + EPB, nE);
    for (int e = e0 + threadIdx.x; e < e1; e += blockDim.x) {
        const int dr = dst[e];
        const int su = src[e];
        if (min(7, (int)(dr * invR)) == p) {
            int pos = off[dr] + atomicSub(&cnt[dr], 1) - 1;
            nbr[pos] = su;
        }
        if (min(7, (int)(su * invU)) == p) {
            int pos = off[Nr + su] + atomicSub(&cnt[Nr + su], 1) - 1;
            nbr[pos] = dr;
        }
    }
}

// ---------------------------------------------------------------------------
// Phase B: atomic-free gather + mean.  16 lanes per node; lane owns 4 feats.
// ---------------------------------------------------------------------------
__device__ __forceinline__ void f4add(float4& a, const float4 v) {
    a.x += v.x; a.y += v.y; a.z += v.z; a.w += v.w;
}

__global__ void gather_mean_kernel(const float* __restrict__ x,
                                   const int* __restrict__ off,
                                   const int* __restrict__ nbr,
                                   float* __restrict__ agg, int N)
{
    const int tid  = blockIdx.x * blockDim.x + threadIdx.x;
    const int g    = tid >> 4;
    if (g >= N) return;
    const int lane = tid & 15;
    const int c    = lane << 2;

    const int beg = off[g];
    const int end = off[g + 1];

    float4 a0 = {0,0,0,0}, a1 = {0,0,0,0}, a2 = {0,0,0,0}, a3 = {0,0,0,0};
    int j = beg;
    for (; j + 4 <= end; j += 4) {
        const int s0 = nbr[j], s1 = nbr[j+1], s2 = nbr[j+2], s3 = nbr[j+3];
        f4add(a0, *reinterpret_cast<const float4*>(x + ((long long)s0 << 6) + c));
        f4add(a1, *reinterpret_cast<const float4*>(x + ((long long)s1 << 6) + c));
        f4add(a2, *reinterpret_cast<const float4*>(x + ((long long)s2 << 6) + c));
        f4add(a3, *reinterpret_cast<const float4*>(x + ((long long)s3 << 6) + c));
    }
    for (; j < end; ++j) {
        f4add(a0, *reinterpret_cast<const float4*>(x + ((long long)nbr[j] << 6) + c));
    }
    f4add(a0, a1); f4add(a2, a3); f4add(a0, a2);

    const float inv = 1.0f / (float)max(end - beg, 1);
    float4 r; r.x = a0.x * inv; r.y = a0.y * inv; r.z = a0.z * inv; r.w = a0.w * inv;
    *reinterpret_cast<float4*>(agg + ((long long)g << 6) + c) = r;
}

// ---------------------------------------------------------------------------
// Phase C (v3): lane = row; 64 accumulators/lane; W via wave-uniform scalar
// loads (s_load). Two passes (Wl over agg, Wr over xroot) cap live row regs.
// In-place safe: lane reads its whole row into regs before writing it.
// ---------------------------------------------------------------------------
__global__ __launch_bounds__(64, 2)
void transform_v3_kernel(const float* __restrict__ agg,
                         const float* __restrict__ xroot,
                         const float* __restrict__ Wl,
                         const float* __restrict__ bl,
                         const float* __restrict__ Wr,
                         float* __restrict__ out, int N)
{
    const int lane = threadIdx.x;                       // 0..63
    const long long r = (long long)blockIdx.x * 64 + lane;
    const bool ok = (r < N);

    float acc[64];
    #pragma unroll
    for (int h = 0; h < 64; ++h) acc[h] = bl[h];        // uniform -> s_load

    // ---- pass 1: acc += agg_row @ Wl ----
    {
        float4 ra[16];
        const float4* pa = reinterpret_cast<const float4*>(agg) + (r << 4);
        #pragma unroll
        for (int i = 0; i < 16; ++i) {
            if (ok) ra[i] = pa[i];
            else { ra[i].x = 0.f; ra[i].y = 0.f; ra[i].z = 0.f; ra[i].w = 0.f; }
        }
        #pragma unroll
        for (int i = 0; i < 16; ++i) {
            #pragma unroll
            for (int j = 0; j < 4; ++j) {
                const int d = i * 4 + j;
                const float rv = (j == 0) ? ra[i].x : (j == 1) ? ra[i].y
                               : (j == 2) ? ra[i].z : ra[i].w;
                #pragma unroll
                for (int h = 0; h < 64; ++h)
                    acc[h] = fmaf(rv, Wl[d * 64 + h], acc[h]);   // W uniform -> SGPR operand
            }
        }
    }

    // ---- pass 2: acc += x_row @ Wr ----
    {
        float4 rx[16];
        const float4* px = reinterpret_cast<const float4*>(xroot) + (r << 4);
        #pragma unroll
        for (int i = 0; i < 16; ++i) {
            if (ok) rx[i] = px[i];
            else { rx[i].x = 0.f; rx[i].y = 0.f; rx[i].z = 0.f; rx[i].w = 0.f; }
        }
        #pragma unroll
        for (int i = 0; i < 16; ++i) {
            #pragma unroll
            for (int j = 0; j < 4; ++j) {
                const int d = i * 4 + j;
                const float rv = (j == 0) ? rx[i].x : (j == 1) ? rx[i].y
                               : (j == 2) ? rx[i].z : rx[i].w;
                #pragma unroll
                for (int h = 0; h < 64; ++h)
                    acc[h] = fmaf(rv, Wr[d * 64 + h], acc[h]);
            }
        }
    }

    // ---- relu + store (lane writes its own contiguous 256B row) ----
    if (ok) {
        float* po = out + (r << 6);
        #pragma unroll
        for (int i = 0; i < 16; ++i) {
            float4 sv;
            sv.x = fmaxf(acc[i * 4 + 0], 0.0f);
            sv.y = fmaxf(acc[i * 4 + 1], 0.0f);
            sv.z = fmaxf(acc[i * 4 + 2], 0.0f);
            sv.w = fmaxf(acc[i * 4 + 3], 0.0f);
            *reinterpret_cast<float4*>(po + i * 4) = sv;
        }
    }
}

// ---------------------------------------------------------------------------
// Fallback (round-1) kernels, used only if ws_size is too small for CSR.
// ---------------------------------------------------------------------------
__global__ void edge_scatter_kernel(
    const float* __restrict__ xu, const float* __restrict__ xr,
    const int* __restrict__ src, const int* __restrict__ dst,
    float* __restrict__ agg_r, float* __restrict__ agg_u,
    float* __restrict__ deg_r, float* __restrict__ deg_u,
    int nE)
{
    int tid  = blockIdx.x * blockDim.x + threadIdx.x;
    int e    = tid >> 4;
    if (e >= nE) return;
    int lane = tid & 15;
    int su = src[e];
    int dr = dst[e];
    if (lane == 0) {
        atomicAdd(&deg_r[dr], 1.0f);
        atomicAdd(&deg_u[su], 1.0f);
    }
    const float4 a = *reinterpret_cast<const float4*>(xu + ((long long)su << 6) + (lane << 2));
    const float4 b = *reinterpret_cast<const float4*>(xr + ((long long)dr << 6) + (lane << 2));
    float* pr = agg_r + ((long long)dr << 6) + (lane << 2);
    float* pu = agg_u + ((long long)su << 6) + (lane << 2);
    atomicAdd(pr + 0, a.x); atomicAdd(pr + 1, a.y);
    atomicAdd(pr + 2, a.z); atomicAdd(pr + 3, a.w);
    atomicAdd(pu + 0, b.x); atomicAdd(pu + 1, b.y);
    atomicAdd(pu + 2, b.z); atomicAdd(pu + 3, b.w);
}

__global__ void transform_kernel(
    const float* __restrict__ agg, const float* __restrict__ deg,
    const float* __restrict__ xroot,
    const float* __restrict__ Wl, const float* __restrict__ bl,
    const float* __restrict__ Wr,
    float* __restrict__ out, int N)
{
    __shared__ float sWl[64 * 64];
    __shared__ float sWr[64 * 64];
    __shared__ float sb[64];
    __shared__ float sAgg[4][64];
    __shared__ float sX[4][64];

    const int t = threadIdx.x;
    for (int i = t; i < 64 * 64; i += 256) {
        sWl[i] = Wl[i];
        sWr[i] = Wr[i];
    }
    if (t < 64) sb[t] = bl[t];
    __syncthreads();

    const int rg = t >> 6;
    const int h  = t & 63;

    for (long long r0 = (long long)blockIdx.x * 4; r0 < N; r0 += (long long)gridDim.x * 4) {
        const long long r = r0 + rg;
        if (r < N) {
            float inv = 1.0f / fmaxf(deg[r], 1.0f);
            sAgg[rg][h] = agg[(r << 6) + h] * inv;
            sX[rg][h]   = xroot[(r << 6) + h];
        }
        __syncthreads();
        if (r < N) {
            float acc = sb[h];
            #pragma unroll
            for (int d = 0; d < 64; ++d) {
                acc += sAgg[rg][d] * sWl[d * 64 + h] + sX[rg][d] * sWr[d * 64 + h];
            }
            out[(r << 6) + h] = fmaxf(acc, 0.0f);
        }
        __syncthreads();
    }
}

extern "C" void kernel_launch(void* const* d_in, const int* in_sizes, int n_in,
                              void* d_out, int out_size, void* d_ws, size_t ws_size,
                              hipStream_t stream)
{
    const float* xu    = (const float*)d_in[0];
    const float* xr    = (const float*)d_in[1];
    const int*   src   = (const int*)  d_in[2];
    const int*   dst   = (const int*)  d_in[3];
    const float* Wl_ur = (const float*)d_in[4];
    const float* bl_ur = (const float*)d_in[5];
    const float* Wr_ur = (const float*)d_in[6];
    const float* Wl_ru = (const float*)d_in[7];
    const float* bl_ru = (const float*)d_in[8];
    const float* Wr_ru = (const float*)d_in[9];

    const int Nu = in_sizes[0] / 64;
    const int Nr = in_sizes[1] / 64;
    const int nE = in_sizes[2];
    const int NN = Nr + Nu;

    float* out   = (float*)d_out;
    float* agg_r = out;                        // [Nr,64]
    float* agg_u = out + (long long)Nr * 64;   // [Nu,64]

    // ---- workspace layout (ints) ----
    int* cnt     = (int*)d_ws;                  // [NN]
    int* off     = cnt + NN;                    // [NN+1]
    int* partial = off + NN + 1;                // [256]
    int* nbr     = partial + 256;               // [2E]
    const size_t need = ((size_t)NN + (size_t)NN + 1 + 256 + 2ull * nE) * sizeof(int);

    if (ws_size >= need) {
        // ---------------- CSR path ----------------
        hipMemsetAsync(cnt, 0, (size_t)NN * sizeof(int), stream);

        const float invR = 8.0f / (float)Nr;
        const float invU = 8.0f / (float)Nu;
        const int nChunks = (nE + EPB - 1) / EPB;
        const int grid    = nChunks * 8;

        count_part_kernel<<<grid, 256, 0, stream>>>(src, dst, cnt, Nr, nE, invR, invU);

        const int nScanBlocks = (NN + SCAN_BS - 1) / SCAN_BS;   // <= 256
        scan_block_kernel<<<nScanBlocks, 256, 0, stream>>>(cnt, off, partial, NN);
        scan_partials_kernel<<<1, 256, 0, stream>>>(partial, nScanBlocks);
        scan_addback_kernel<<<(NN + 255) / 256, 256, 0, stream>>>(off, partial, NN, 2 * nE);

        scatter_part_kernel<<<grid, 256, 0, stream>>>(src, dst, off, cnt, nbr, Nr, nE, invR, invU);

        // gathers (mean fused in; writes every output row)
        {
            const long long tr = (long long)Nr * 16;
            gather_mean_kernel<<<(int)((tr + 255) / 256), 256, 0, stream>>>(
                xu, off, nbr, agg_r, Nr);
            const long long tu = (long long)Nu * 16;
            gather_mean_kernel<<<(int)((tu + 255) / 256), 256, 0, stream>>>(
                xr, off + Nr, nbr, agg_u, Nu);
        }

        transform_v3_kernel<<<(Nr + 63) / 64, 64, 0, stream>>>(
            agg_r, xr, Wl_ur, bl_ur, Wr_ur, agg_r, Nr);
        transform_v3_kernel<<<(Nu + 63) / 64, 64, 0, stream>>>(
            agg_u, xu, Wl_ru, bl_ru, Wr_ru, agg_u, Nu);
    } else {
        // ---------------- fallback: atomic path ----------------
        float* deg_r = (float*)d_ws;
        float* deg_u = deg_r + Nr;
        hipMemsetAsync(d_out, 0, (size_t)out_size * sizeof(float), stream);
        hipMemsetAsync(d_ws, 0, (size_t)NN * sizeof(float), stream);

        const long long total = (long long)nE * 16;
        edge_scatter_kernel<<<(int)((total + 255) / 256), 256, 0, stream>>>(
            xu, xr, src, dst, agg_r, agg_u, deg_r, deg_u, nE);

        transform_kernel<<<2048, 256, 0, stream>>>(
            agg_r, deg_r, xr, Wl_ur, bl_ur, Wr_ur, agg_r, Nr);
        transform_kernel<<<2048, 256, 0, stream>>>(
            agg_u, deg_u, xu, Wl_ru, bl_ru, Wr_ru, agg_u, Nu);
    }
}